// Round 2
// baseline (409.468 us; speedup 1.0000x reference)
//
#include <hip/hip_runtime.h>

// SelfAttention: X[8192,1024] -> Q,K,V = X@W^T+b ; P=exp(cosine(Q,K)) ; out = P@V / rowsum(P)
// R10 = R9 + int8 P and int8 V for the PV GEMM (out_kernel now uses the R9-proven i8 core).
//  - scores = cosine of quantized int vectors -> |s|<=1 exactly -> exp in [1/e, e]:
//    P quantized with s_P = 127/e (no clip possible). V quantized with s_V = 127/6.
//  - scale algebra: out = sum(qP*qV) / (s_V * sum(qP)) — s_P cancels; denom = int sum of qP.
//  - P8 = 64 MB (was 135 bf16): R9's out showed FETCH 533 MB / 3.37 TB/s = whole-kernel
//    HBM transfer; halving operand bytes + halving MFMA instructions attacks both.
//  - epilogues reuse the proven qkv-Q8 pattern (bf16 LDS transpose -> readback -> quantize
//    -> packed int2 stores). Error budget: +1.7e-4 std -> absmax ~1e-3 < 1.52e-3 threshold.
// R11/R12: identical resubmits — R10/R11 benches lost to GPUAcquisitionTimeout (infra);
//      re-measuring to capture the R10 counter breakdown before the 8-phase core port.
//      Pre-commit: if this round also infra-fails, R13 ships the 8-phase i8 core port.

#define SEQ 8192
#define MID 1024
#define EMB 1024

typedef __attribute__((ext_vector_type(8))) short short8x;
typedef __attribute__((ext_vector_type(16))) float float16x;
typedef __attribute__((ext_vector_type(4))) int int4x;
typedef __attribute__((ext_vector_type(16))) int int16x;

__device__ __forceinline__ unsigned short f2bf(float x) {
  union { float f; unsigned u; } v; v.f = x;
  unsigned r = v.u + 0x7FFFu + ((v.u >> 16) & 1u);  // round-to-nearest-even
  return (unsigned short)(r >> 16);
}
__device__ __forceinline__ float bf2f(unsigned short h) {
  union { unsigned u; float f; } v; v.u = ((unsigned)h) << 16;
  return v.f;
}

__device__ __forceinline__ void g2l16(const void* g, void* lds) {
  __builtin_amdgcn_global_load_lds(
      (const __attribute__((address_space(1))) unsigned int*)g,
      (__attribute__((address_space(3))) unsigned int*)lds, 16, 0, 0);
}

// ---------------- 128x128 bf16 NT GEMM core (qkv) ----------------
__device__ __forceinline__ void gemm128_nt(
    const unsigned short* __restrict__ A, const unsigned short* __restrict__ B,
    long lda, long ldb, int m0, int n0, int K,
    unsigned short* As, unsigned short* Bs, float16x acc[2][2]) {
  const int tid = threadIdx.x;
  const int w = tid >> 6;
  const int l = tid & 63;
  const int wm = (w & 1) << 6;
  const int wn = (w >> 1) << 6;
  const int srow = l >> 3;
  const int skg = (l & 7) ^ srow;
  const int l31 = l & 31;
  const int lh = l >> 5;
  const int swz = l31 & 7;

  for (int k0 = 0; k0 < K; k0 += 64) {
    __syncthreads();
#pragma unroll
    for (int r = 0; r < 4; ++r) {
      const int rr = (w * 4 + r) * 8 + srow;
      g2l16(A + (long)(m0 + rr) * lda + k0 + skg * 8, As + (w * 4 + r) * 512);
      g2l16(B + (long)(n0 + rr) * ldb + k0 + skg * 8, Bs + (w * 4 + r) * 512);
    }
    __syncthreads();
#pragma unroll
    for (int ks = 0; ks < 4; ++ks) {
      const int kg = ks * 2 + lh;
      short8x av[2], bv[2];
#pragma unroll
      for (int t = 0; t < 2; ++t) {
        av[t] = *(const short8x*)(As + (wm + t * 32 + l31) * 64 + ((kg ^ swz) << 3));
        bv[t] = *(const short8x*)(Bs + (wn + t * 32 + l31) * 64 + ((kg ^ swz) << 3));
      }
#pragma unroll
      for (int tm = 0; tm < 2; ++tm)
#pragma unroll
        for (int tn = 0; tn < 2; ++tn)
          acc[tm][tn] = __builtin_amdgcn_mfma_f32_32x32x16_bf16(av[tm], bv[tn], acc[tm][tn], 0, 0, 0);
    }
  }
}

// ---------------- 128x128 i8 NT GEMM core (score, out) — R9-proven ----------------
__device__ __forceinline__ void gemm128_nt_i8(
    const unsigned char* __restrict__ A, const unsigned char* __restrict__ B,
    long lda, long ldb, int m0, int n0, int Kbytes,
    unsigned char* As, unsigned char* Bs, int16x acc[2][2]) {
  const int tid = threadIdx.x;
  const int w = tid >> 6;
  const int l = tid & 63;
  const int wm = (w & 1) << 6;
  const int wn = (w >> 1) << 6;
  const int srow = l >> 3;
  const int skg = (l & 7) ^ srow;
  const int l31 = l & 31;
  const int lh = l >> 5;
  const int swz = l31 & 7;

  for (int k0 = 0; k0 < Kbytes; k0 += 128) {
    __syncthreads();
#pragma unroll
    for (int r = 0; r < 4; ++r) {
      const int rr = (w * 4 + r) * 8 + srow;
      g2l16(A + (long)(m0 + rr) * lda + k0 + skg * 16, As + (w * 4 + r) * 1024);
      g2l16(B + (long)(n0 + rr) * ldb + k0 + skg * 16, Bs + (w * 4 + r) * 1024);
    }
    __syncthreads();
#pragma unroll
    for (int ks = 0; ks < 4; ++ks) {
      const int kg = ks * 2 + lh;
      int4x av[2], bv[2];
#pragma unroll
      for (int t = 0; t < 2; ++t) {
        av[t] = *(const int4x*)(As + (wm + t * 32 + l31) * 128 + ((kg ^ swz) << 4));
        bv[t] = *(const int4x*)(Bs + (wn + t * 32 + l31) * 128 + ((kg ^ swz) << 4));
      }
#pragma unroll
      for (int tm = 0; tm < 2; ++tm)
#pragma unroll
        for (int tn = 0; tn < 2; ++tn)
          acc[tm][tn] = __builtin_amdgcn_mfma_i32_32x32x32_i8(av[tm], bv[tn], acc[tm][tn], 0, 0, 0);
    }
  }
}

// One launch: convert X + Wq/Wk/Wv to bf16, and zero sums (24576 floats).
__global__ void cvt_all(const float* __restrict__ X,
                        const float* __restrict__ wq, const float* __restrict__ wk,
                        const float* __restrict__ wv,
                        unsigned short* __restrict__ Xb, unsigned short* __restrict__ Wb,
                        float* __restrict__ sums) {
  const long i = ((long)blockIdx.x * 256 + threadIdx.x) * 4;
  if (i < 24576) *(float4*)(sums + i) = (float4){0.f, 0.f, 0.f, 0.f};
  const float* src;
  unsigned short* dst;
  long off;
  if (i < (long)SEQ * EMB) {
    src = X; dst = Xb; off = i;
  } else {
    long j = i - (long)SEQ * EMB;
    int t = (int)(j >> 20);
    off = j & (MID * EMB - 1);
    src = (t == 0) ? wq : (t == 1) ? wk : wv;
    dst = Wb + (long)t * MID * EMB;
  }
  float4 v = *(const float4*)(src + off);
  ushort4 o;
  o.x = f2bf(v.x); o.y = f2bf(v.y); o.z = f2bf(v.z); o.w = f2bf(v.w);
  *(ushort4*)(dst + off) = o;
}

__global__ __launch_bounds__(256) void qkv_kernel(
    const unsigned short* __restrict__ Xb, const unsigned short* __restrict__ Wb,
    const float* __restrict__ bq, const float* __restrict__ bk, const float* __restrict__ bv,
    unsigned char* __restrict__ Q8, unsigned char* __restrict__ K8,
    unsigned char* __restrict__ VT8, float* __restrict__ sumsq) {
  __shared__ unsigned short smem[16384];
  unsigned short* As = smem;
  unsigned short* Bs = smem + 8192;
  const int z = blockIdx.z;
  const int m0 = blockIdx.y * 128;
  const int n0 = blockIdx.x * 128;
  float16x acc[2][2];
#pragma unroll
  for (int i = 0; i < 2; ++i)
#pragma unroll
    for (int j = 0; j < 2; ++j)
#pragma unroll
      for (int e = 0; e < 16; ++e) acc[i][j][e] = 0.f;

  gemm128_nt(Xb, Wb + (long)z * MID * EMB, EMB, EMB, m0, n0, EMB, As, Bs, acc);

  const int tid = threadIdx.x;
  const int l = tid & 63, w = tid >> 6;
  const int wm = (w & 1) << 6, wn = (w >> 1) << 6;
  const int l31 = l & 31, lh = l >> 5;
  const float* bias = (z == 0) ? bq : (z == 1) ? bk : bv;
  float bvv[2];
#pragma unroll
  for (int tn = 0; tn < 2; ++tn) bvv[tn] = bias[n0 + wn + tn * 32 + l31];
#pragma unroll
  for (int tm = 0; tm < 2; ++tm)
#pragma unroll
    for (int tn = 0; tn < 2; ++tn)
#pragma unroll
      for (int r = 0; r < 16; ++r) acc[tm][tn][r] += bvv[tn];

  __syncthreads();  // all waves done reading As/Bs

  if (z < 2) {
    // bf16 transpose tile, then readback -> int8 quantize + int-sumsq (R9-proven)
#pragma unroll
    for (int tm = 0; tm < 2; ++tm)
#pragma unroll
      for (int tn = 0; tn < 2; ++tn) {
        const int rcol = wn + tn * 32 + l31;
#pragma unroll
        for (int r = 0; r < 16; ++r) {
          float v = acc[tm][tn][r];
          float po = __shfl_xor(v, 1);
          if (!(l & 1)) {
            const int rrow = wm + tm * 32 + (r & 3) + 8 * (r >> 2) + 4 * lh;
            const int chunk = (rcol >> 3) ^ (rrow & 7);
            unsigned pk = (unsigned)f2bf(v) | ((unsigned)f2bf(po) << 16);
            *(unsigned*)(smem + rrow * 128 + (chunk << 3) + (rcol & 7)) = pk;
          }
        }
      }
    __syncthreads();
    unsigned char* O8 = z ? K8 : Q8;
    float* ss = sumsq + (long)z * SEQ;
    const float qs = 127.0f / 8.0f;
#pragma unroll
    for (int round = 0; round < 8; ++round) {
      const int row = round * 16 + (tid >> 4);
      const int c = tid & 15;
      short8x vv = *(const short8x*)(smem + row * 128 + ((c ^ (row & 7)) << 3));
      int qq[8];
      float s = 0.f;
#pragma unroll
      for (int j = 0; j < 8; ++j) {
        float t = rintf(bf2f((unsigned short)vv[j]) * qs);
        t = fminf(127.f, fmaxf(-127.f, t));
        qq[j] = (int)t;
        s += t * t;
      }
      unsigned lo = (qq[0] & 255) | ((qq[1] & 255) << 8) | ((qq[2] & 255) << 16) | ((qq[3] & 255) << 24);
      unsigned hi = (qq[4] & 255) | ((qq[5] & 255) << 8) | ((qq[6] & 255) << 16) | ((qq[7] & 255) << 24);
      int2 pk; pk.x = (int)lo; pk.y = (int)hi;
      *(int2*)(O8 + (long)(m0 + row) * MID + n0 + c * 8) = pk;
      s += __shfl_xor(s, 1); s += __shfl_xor(s, 2);
      s += __shfl_xor(s, 4); s += __shfl_xor(s, 8);
      if (c == 0) atomicAdd(ss + m0 + row, s);
    }
  } else {
    // V transposed, int8: bf16 LDS tile [nn][mm] (proven), readback -> quantize -> VT8
#pragma unroll
    for (int tm = 0; tm < 2; ++tm)
#pragma unroll
      for (int tn = 0; tn < 2; ++tn) {
        const int nn = wn + tn * 32 + l31;
#pragma unroll
        for (int g = 0; g < 4; ++g) {
          const int mm = wm + tm * 32 + 8 * g + 4 * lh;
          const int chunk = (mm >> 3) ^ (nn & 7);
          ushort4 pk;
          pk.x = f2bf(acc[tm][tn][g * 4 + 0]);
          pk.y = f2bf(acc[tm][tn][g * 4 + 1]);
          pk.z = f2bf(acc[tm][tn][g * 4 + 2]);
          pk.w = f2bf(acc[tm][tn][g * 4 + 3]);
          *(ushort4*)(smem + nn * 128 + (chunk << 3) + (mm & 7)) = pk;
        }
      }
    __syncthreads();
    const float vs = 127.0f / 6.0f;  // |V| <= ~5.5 over 8M N(0,1)-ish samples
#pragma unroll
    for (int round = 0; round < 8; ++round) {
      const int nn = round * 16 + (tid >> 4);
      const int c = tid & 15;
      short8x vv = *(const short8x*)(smem + nn * 128 + ((c ^ (nn & 7)) << 3));
      int qq[8];
#pragma unroll
      for (int j = 0; j < 8; ++j) {
        float t = rintf(bf2f((unsigned short)vv[j]) * vs);
        t = fminf(127.f, fmaxf(-127.f, t));
        qq[j] = (int)t;
      }
      unsigned lo = (qq[0] & 255) | ((qq[1] & 255) << 8) | ((qq[2] & 255) << 16) | ((qq[3] & 255) << 24);
      unsigned hi = (qq[4] & 255) | ((qq[5] & 255) << 8) | ((qq[6] & 255) << 16) | ((qq[7] & 255) << 24);
      int2 pk; pk.x = (int)lo; pk.y = (int)hi;
      *(int2*)(VT8 + (long)(n0 + nn) * SEQ + m0 + c * 8) = pk;
    }
  }
}

__global__ __launch_bounds__(256) void score_kernel(
    const unsigned char* __restrict__ Q8, const unsigned char* __restrict__ K8,
    const float* __restrict__ sumsq,
    unsigned char* __restrict__ P8, float* __restrict__ denomq) {
  __shared__ unsigned short smem[16384];  // i8 As/Bs (16K+16K), then bf16 exp tile
  unsigned char* As = (unsigned char*)smem;
  unsigned char* Bs = (unsigned char*)smem + 16384;
  const int m0 = blockIdx.y * 128;
  const int n0 = blockIdx.x * 128;
  int16x acc[2][2];
#pragma unroll
  for (int i = 0; i < 2; ++i)
#pragma unroll
    for (int j = 0; j < 2; ++j)
#pragma unroll
      for (int e = 0; e < 16; ++e) acc[i][j][e] = 0;

  gemm128_nt_i8(Q8, K8, MID, MID, m0, n0, MID, As, Bs, acc);

  const int tid = threadIdx.x;
  const int l = tid & 63, w = tid >> 6;
  const int wm = (w & 1) << 6, wn = (w >> 1) << 6;
  const int l31 = l & 31, lh = l >> 5;

  float ik[2];
#pragma unroll
  for (int tn = 0; tn < 2; ++tn)
    ik[tn] = rsqrtf(sumsq[SEQ + n0 + wn + tn * 32 + l31]);

  __syncthreads();  // all waves done reading As/Bs

  // exp(cos) in [1/e, e] -> bf16 LDS tile (proven transform path)
#pragma unroll
  for (int tm = 0; tm < 2; ++tm)
#pragma unroll
    for (int r = 0; r < 16; ++r) {
      const int rrow = wm + tm * 32 + (r & 3) + 8 * (r >> 2) + 4 * lh;
      const float qi = rsqrtf(sumsq[m0 + rrow]);
#pragma unroll
      for (int tn = 0; tn < 2; ++tn) {
        float v = __expf((float)acc[tm][tn][r] * qi * ik[tn]);
        float po = __shfl_xor(v, 1);
        if (!(l & 1)) {
          const int rcol = wn + tn * 32 + l31;  // even
          const int chunk = (rcol >> 3) ^ (rrow & 7);
          unsigned pk = (unsigned)f2bf(v) | ((unsigned)f2bf(po) << 16);
          *(unsigned*)(smem + rrow * 128 + (chunk << 3) + (rcol & 7)) = pk;
        }
      }
    }
  __syncthreads();
  // readback -> int8 quantize (s_P = 127/e, q in [17,127]) + denom = int row sum
  const float ps = 127.0f / 2.7182818f;
#pragma unroll
  for (int round = 0; round < 8; ++round) {
    const int row = round * 16 + (tid >> 4);
    const int c = tid & 15;
    short8x vv = *(const short8x*)(smem + row * 128 + ((c ^ (row & 7)) << 3));
    int qq[8];
    float s = 0.f;
#pragma unroll
    for (int j = 0; j < 8; ++j) {
      float t = rintf(bf2f((unsigned short)vv[j]) * ps);
      t = fminf(127.f, t);
      qq[j] = (int)t;
      s += t;
    }
    unsigned lo = (qq[0] & 255) | ((qq[1] & 255) << 8) | ((qq[2] & 255) << 16) | ((qq[3] & 255) << 24);
    unsigned hi = (qq[4] & 255) | ((qq[5] & 255) << 8) | ((qq[6] & 255) << 16) | ((qq[7] & 255) << 24);
    int2 pk; pk.x = (int)lo; pk.y = (int)hi;
    *(int2*)(P8 + (long)(m0 + row) * SEQ + n0 + c * 8) = pk;
    s += __shfl_xor(s, 1); s += __shfl_xor(s, 2);
    s += __shfl_xor(s, 4); s += __shfl_xor(s, 8);
    if (c == 0) atomicAdd(denomq + m0 + row, s);
  }
}

__global__ __launch_bounds__(256) void out_kernel(
    const unsigned char* __restrict__ P8, const unsigned char* __restrict__ VT8,
    const float* __restrict__ denomq, float* __restrict__ out) {
  __shared__ unsigned char smem8[32768];  // i8 As/Bs 16K+16K
  unsigned char* As = smem8;
  unsigned char* Bs = smem8 + 16384;
  // grid: x = n (fast, 8), y = m (64) -> XCD = n%8: VT8 slice (1 MB) L2-pinned per XCD
  const int n0 = blockIdx.x * 128;
  const int m0 = blockIdx.y * 128;
  int16x acc[2][2];
#pragma unroll
  for (int i = 0; i < 2; ++i)
#pragma unroll
    for (int j = 0; j < 2; ++j)
#pragma unroll
      for (int e = 0; e < 16; ++e) acc[i][j][e] = 0;

  gemm128_nt_i8(P8, VT8, SEQ, SEQ, m0, n0, SEQ, As, Bs, acc);

  const int l = threadIdx.x & 63, w = threadIdx.x >> 6;
  const int wm = (w & 1) << 6, wn = (w >> 1) << 6;
  const int l31 = l & 31, lh = l >> 5;
  const float sv = 127.0f / 6.0f;
#pragma unroll
  for (int tm = 0; tm < 2; ++tm)
#pragma unroll
    for (int r = 0; r < 16; ++r) {
      const int row = m0 + wm + tm * 32 + (r & 3) + 8 * (r >> 2) + 4 * lh;
      const float inv = 1.0f / (sv * denomq[row]);   // out = sum(qP*qV) / (s_V * sum(qP))
#pragma unroll
      for (int tn = 0; tn < 2; ++tn) {
        const int col = n0 + wn + tn * 32 + l31;
        out[(long)row * MID + col] = (float)acc[tm][tn][r] * inv;
      }
    }
}

extern "C" void kernel_launch(void* const* d_in, const int* in_sizes, int n_in,
                              void* d_out, int out_size, void* d_ws, size_t ws_size,
                              hipStream_t stream) {
  const float* X  = (const float*)d_in[0];
  const float* Wq = (const float*)d_in[1];
  const float* bq = (const float*)d_in[2];
  const float* Wk = (const float*)d_in[3];
  const float* bk = (const float*)d_in[4];
  const float* Wv = (const float*)d_in[5];
  const float* bv = (const float*)d_in[6];

  // workspace layout (bytes). Xb/Wb alias the P8 region: dead before score writes P8.
  //  [0,8M)    Q8 int8 [8192][1024]
  //  [8M,16M)  K8 int8
  //  [16M,24M) VT8 int8 [1024][8192]
  //  [24M,..)  sumsq_q[8192], sumsq_k[8192], denomq[8192]  fp32 (zeroed by cvt_all)
  //  [25M,89M) P8 int8 [8192][8192];  Xb at 25M (16M), Wb at 41M (6M) alias inside
  char* wsb = (char*)d_ws;
  const size_t MB = 1ull << 20;
  unsigned char* Q8  = (unsigned char*)(wsb);
  unsigned char* K8  = (unsigned char*)(wsb + 8 * MB);
  unsigned char* VT8 = (unsigned char*)(wsb + 16 * MB);
  float* sums        = (float*)(wsb + 24 * MB);
  float* denomq      = sums + 2 * SEQ;
  unsigned char* P8  = (unsigned char*)(wsb + 25 * MB);
  unsigned short* Xb = (unsigned short*)(wsb + 25 * MB);
  unsigned short* Wb = (unsigned short*)(wsb + 41 * MB);

  const int cvt_elems = SEQ * EMB + 3 * MID * EMB;
  cvt_all<<<cvt_elems / 1024, 256, 0, stream>>>(X, Wq, Wk, Wv, Xb, Wb, sums);

  qkv_kernel<<<dim3(MID / 128, SEQ / 128, 3), 256, 0, stream>>>(Xb, Wb, bq, bk, bv, Q8, K8, VT8, sums);
  score_kernel<<<dim3(SEQ / 128, SEQ / 128), 256, 0, stream>>>(Q8, K8, sums, P8, denomq);
  out_kernel<<<dim3(MID / 128, SEQ / 128), 256, 0, stream>>>(P8, VT8, denomq, (float*)d_out);
}

// Round 3
// 344.087 us; speedup vs baseline: 1.1900x; 1.1900x over previous
//
#include <hip/hip_runtime.h>

// SelfAttention: X[8192,1024] -> Q,K,V = X@W^T+b ; P=exp(cosine(Q,K)) ; out = P@V / rowsum(P)
// R10: int8 P / int8 V PV GEMM (i8 core for score+out). absmax 9.77e-4, 409 us measured.
// R13 (this round): score_kernel epilogue rewrite — counters showed score = 186 us with
//   MfmaUtil 15.6% (GEMM floor ~31 us) and VALUBusy 33.7%: epilogue-VALU/latency bound.
//   - GEMM operand swap (A=K8, B=Q8): acc reg-axis = K index, 4 consecutive regs = 4
//     consecutive P8 bytes -> row-major u32 pack in-register, NO cross-lane transpose,
//     no bf16 round-trip.
//   - magic-number quantize: q = low byte of (exp2(dot*ik*qi*log2e + log2(127/e)) + 1.5*2^23).
//     cos<=1 exactly (int Cauchy-Schwarz) -> q in [17,127], no clamp.
//   - denom = sum of quantized bytes via masked 16-bit-lane adds during readback.
//   - readback: b128 LDS reads + dwordx4 P8 stores (16B/lane), 16B-granular XOR swizzle.
//   GEMM core / grid / other kernels byte-identical.

#define SEQ 8192
#define MID 1024
#define EMB 1024

typedef __attribute__((ext_vector_type(8))) short short8x;
typedef __attribute__((ext_vector_type(16))) float float16x;
typedef __attribute__((ext_vector_type(4))) int int4x;
typedef __attribute__((ext_vector_type(16))) int int16x;

__device__ __forceinline__ unsigned short f2bf(float x) {
  union { float f; unsigned u; } v; v.f = x;
  unsigned r = v.u + 0x7FFFu + ((v.u >> 16) & 1u);  // round-to-nearest-even
  return (unsigned short)(r >> 16);
}
__device__ __forceinline__ float bf2f(unsigned short h) {
  union { unsigned u; float f; } v; v.u = ((unsigned)h) << 16;
  return v.f;
}
__device__ __forceinline__ float fexp2(float x) {
#if __has_builtin(__builtin_amdgcn_exp2f)
  return __builtin_amdgcn_exp2f(x);
#else
  return __expf(x * 0.6931471805599453f);
#endif
}

__device__ __forceinline__ void g2l16(const void* g, void* lds) {
  __builtin_amdgcn_global_load_lds(
      (const __attribute__((address_space(1))) unsigned int*)g,
      (__attribute__((address_space(3))) unsigned int*)lds, 16, 0, 0);
}

// ---------------- 128x128 bf16 NT GEMM core (qkv) ----------------
__device__ __forceinline__ void gemm128_nt(
    const unsigned short* __restrict__ A, const unsigned short* __restrict__ B,
    long lda, long ldb, int m0, int n0, int K,
    unsigned short* As, unsigned short* Bs, float16x acc[2][2]) {
  const int tid = threadIdx.x;
  const int w = tid >> 6;
  const int l = tid & 63;
  const int wm = (w & 1) << 6;
  const int wn = (w >> 1) << 6;
  const int srow = l >> 3;
  const int skg = (l & 7) ^ srow;
  const int l31 = l & 31;
  const int lh = l >> 5;
  const int swz = l31 & 7;

  for (int k0 = 0; k0 < K; k0 += 64) {
    __syncthreads();
#pragma unroll
    for (int r = 0; r < 4; ++r) {
      const int rr = (w * 4 + r) * 8 + srow;
      g2l16(A + (long)(m0 + rr) * lda + k0 + skg * 8, As + (w * 4 + r) * 512);
      g2l16(B + (long)(n0 + rr) * ldb + k0 + skg * 8, Bs + (w * 4 + r) * 512);
    }
    __syncthreads();
#pragma unroll
    for (int ks = 0; ks < 4; ++ks) {
      const int kg = ks * 2 + lh;
      short8x av[2], bv[2];
#pragma unroll
      for (int t = 0; t < 2; ++t) {
        av[t] = *(const short8x*)(As + (wm + t * 32 + l31) * 64 + ((kg ^ swz) << 3));
        bv[t] = *(const short8x*)(Bs + (wn + t * 32 + l31) * 64 + ((kg ^ swz) << 3));
      }
#pragma unroll
      for (int tm = 0; tm < 2; ++tm)
#pragma unroll
        for (int tn = 0; tn < 2; ++tn)
          acc[tm][tn] = __builtin_amdgcn_mfma_f32_32x32x16_bf16(av[tm], bv[tn], acc[tm][tn], 0, 0, 0);
    }
  }
}

// ---------------- 128x128 i8 NT GEMM core (score, out) — R9-proven ----------------
__device__ __forceinline__ void gemm128_nt_i8(
    const unsigned char* __restrict__ A, const unsigned char* __restrict__ B,
    long lda, long ldb, int m0, int n0, int Kbytes,
    unsigned char* As, unsigned char* Bs, int16x acc[2][2]) {
  const int tid = threadIdx.x;
  const int w = tid >> 6;
  const int l = tid & 63;
  const int wm = (w & 1) << 6;
  const int wn = (w >> 1) << 6;
  const int srow = l >> 3;
  const int skg = (l & 7) ^ srow;
  const int l31 = l & 31;
  const int lh = l >> 5;
  const int swz = l31 & 7;

  for (int k0 = 0; k0 < Kbytes; k0 += 128) {
    __syncthreads();
#pragma unroll
    for (int r = 0; r < 4; ++r) {
      const int rr = (w * 4 + r) * 8 + srow;
      g2l16(A + (long)(m0 + rr) * lda + k0 + skg * 16, As + (w * 4 + r) * 1024);
      g2l16(B + (long)(n0 + rr) * ldb + k0 + skg * 16, Bs + (w * 4 + r) * 1024);
    }
    __syncthreads();
#pragma unroll
    for (int ks = 0; ks < 4; ++ks) {
      const int kg = ks * 2 + lh;
      int4x av[2], bv[2];
#pragma unroll
      for (int t = 0; t < 2; ++t) {
        av[t] = *(const int4x*)(As + (wm + t * 32 + l31) * 128 + ((kg ^ swz) << 4));
        bv[t] = *(const int4x*)(Bs + (wn + t * 32 + l31) * 128 + ((kg ^ swz) << 4));
      }
#pragma unroll
      for (int tm = 0; tm < 2; ++tm)
#pragma unroll
        for (int tn = 0; tn < 2; ++tn)
          acc[tm][tn] = __builtin_amdgcn_mfma_i32_32x32x32_i8(av[tm], bv[tn], acc[tm][tn], 0, 0, 0);
    }
  }
}

// One launch: convert X + Wq/Wk/Wv to bf16, and zero sums (24576 floats).
__global__ void cvt_all(const float* __restrict__ X,
                        const float* __restrict__ wq, const float* __restrict__ wk,
                        const float* __restrict__ wv,
                        unsigned short* __restrict__ Xb, unsigned short* __restrict__ Wb,
                        float* __restrict__ sums) {
  const long i = ((long)blockIdx.x * 256 + threadIdx.x) * 4;
  if (i < 24576) *(float4*)(sums + i) = (float4){0.f, 0.f, 0.f, 0.f};
  const float* src;
  unsigned short* dst;
  long off;
  if (i < (long)SEQ * EMB) {
    src = X; dst = Xb; off = i;
  } else {
    long j = i - (long)SEQ * EMB;
    int t = (int)(j >> 20);
    off = j & (MID * EMB - 1);
    src = (t == 0) ? wq : (t == 1) ? wk : wv;
    dst = Wb + (long)t * MID * EMB;
  }
  float4 v = *(const float4*)(src + off);
  ushort4 o;
  o.x = f2bf(v.x); o.y = f2bf(v.y); o.z = f2bf(v.z); o.w = f2bf(v.w);
  *(ushort4*)(dst + off) = o;
}

__global__ __launch_bounds__(256) void qkv_kernel(
    const unsigned short* __restrict__ Xb, const unsigned short* __restrict__ Wb,
    const float* __restrict__ bq, const float* __restrict__ bk, const float* __restrict__ bv,
    unsigned char* __restrict__ Q8, unsigned char* __restrict__ K8,
    unsigned char* __restrict__ VT8, float* __restrict__ sumsq) {
  __shared__ unsigned short smem[16384];
  unsigned short* As = smem;
  unsigned short* Bs = smem + 8192;
  const int z = blockIdx.z;
  const int m0 = blockIdx.y * 128;
  const int n0 = blockIdx.x * 128;
  float16x acc[2][2];
#pragma unroll
  for (int i = 0; i < 2; ++i)
#pragma unroll
    for (int j = 0; j < 2; ++j)
#pragma unroll
      for (int e = 0; e < 16; ++e) acc[i][j][e] = 0.f;

  gemm128_nt(Xb, Wb + (long)z * MID * EMB, EMB, EMB, m0, n0, EMB, As, Bs, acc);

  const int tid = threadIdx.x;
  const int l = tid & 63, w = tid >> 6;
  const int wm = (w & 1) << 6, wn = (w >> 1) << 6;
  const int l31 = l & 31, lh = l >> 5;
  const float* bias = (z == 0) ? bq : (z == 1) ? bk : bv;
  float bvv[2];
#pragma unroll
  for (int tn = 0; tn < 2; ++tn) bvv[tn] = bias[n0 + wn + tn * 32 + l31];
#pragma unroll
  for (int tm = 0; tm < 2; ++tm)
#pragma unroll
    for (int tn = 0; tn < 2; ++tn)
#pragma unroll
      for (int r = 0; r < 16; ++r) acc[tm][tn][r] += bvv[tn];

  __syncthreads();  // all waves done reading As/Bs

  if (z < 2) {
    // bf16 transpose tile, then readback -> int8 quantize + int-sumsq (R9-proven)
#pragma unroll
    for (int tm = 0; tm < 2; ++tm)
#pragma unroll
      for (int tn = 0; tn < 2; ++tn) {
        const int rcol = wn + tn * 32 + l31;
#pragma unroll
        for (int r = 0; r < 16; ++r) {
          float v = acc[tm][tn][r];
          float po = __shfl_xor(v, 1);
          if (!(l & 1)) {
            const int rrow = wm + tm * 32 + (r & 3) + 8 * (r >> 2) + 4 * lh;
            const int chunk = (rcol >> 3) ^ (rrow & 7);
            unsigned pk = (unsigned)f2bf(v) | ((unsigned)f2bf(po) << 16);
            *(unsigned*)(smem + rrow * 128 + (chunk << 3) + (rcol & 7)) = pk;
          }
        }
      }
    __syncthreads();
    unsigned char* O8 = z ? K8 : Q8;
    float* ss = sumsq + (long)z * SEQ;
    const float qs = 127.0f / 8.0f;
#pragma unroll
    for (int round = 0; round < 8; ++round) {
      const int row = round * 16 + (tid >> 4);
      const int c = tid & 15;
      short8x vv = *(const short8x*)(smem + row * 128 + ((c ^ (row & 7)) << 3));
      int qq[8];
      float s = 0.f;
#pragma unroll
      for (int j = 0; j < 8; ++j) {
        float t = rintf(bf2f((unsigned short)vv[j]) * qs);
        t = fminf(127.f, fmaxf(-127.f, t));
        qq[j] = (int)t;
        s += t * t;
      }
      unsigned lo = (qq[0] & 255) | ((qq[1] & 255) << 8) | ((qq[2] & 255) << 16) | ((qq[3] & 255) << 24);
      unsigned hi = (qq[4] & 255) | ((qq[5] & 255) << 8) | ((qq[6] & 255) << 16) | ((qq[7] & 255) << 24);
      int2 pk; pk.x = (int)lo; pk.y = (int)hi;
      *(int2*)(O8 + (long)(m0 + row) * MID + n0 + c * 8) = pk;
      s += __shfl_xor(s, 1); s += __shfl_xor(s, 2);
      s += __shfl_xor(s, 4); s += __shfl_xor(s, 8);
      if (c == 0) atomicAdd(ss + m0 + row, s);
    }
  } else {
    // V transposed, int8: bf16 LDS tile [nn][mm] (proven), readback -> quantize -> VT8
#pragma unroll
    for (int tm = 0; tm < 2; ++tm)
#pragma unroll
      for (int tn = 0; tn < 2; ++tn) {
        const int nn = wn + tn * 32 + l31;
#pragma unroll
        for (int g = 0; g < 4; ++g) {
          const int mm = wm + tm * 32 + 8 * g + 4 * lh;
          const int chunk = (mm >> 3) ^ (nn & 7);
          ushort4 pk;
          pk.x = f2bf(acc[tm][tn][g * 4 + 0]);
          pk.y = f2bf(acc[tm][tn][g * 4 + 1]);
          pk.z = f2bf(acc[tm][tn][g * 4 + 2]);
          pk.w = f2bf(acc[tm][tn][g * 4 + 3]);
          *(ushort4*)(smem + nn * 128 + (chunk << 3) + (mm & 7)) = pk;
        }
      }
    __syncthreads();
    const float vs = 127.0f / 6.0f;  // |V| <= ~5.5 over 8M N(0,1)-ish samples
#pragma unroll
    for (int round = 0; round < 8; ++round) {
      const int nn = round * 16 + (tid >> 4);
      const int c = tid & 15;
      short8x vv = *(const short8x*)(smem + nn * 128 + ((c ^ (nn & 7)) << 3));
      int qq[8];
#pragma unroll
      for (int j = 0; j < 8; ++j) {
        float t = rintf(bf2f((unsigned short)vv[j]) * vs);
        t = fminf(127.f, fmaxf(-127.f, t));
        qq[j] = (int)t;
      }
      unsigned lo = (qq[0] & 255) | ((qq[1] & 255) << 8) | ((qq[2] & 255) << 16) | ((qq[3] & 255) << 24);
      unsigned hi = (qq[4] & 255) | ((qq[5] & 255) << 8) | ((qq[6] & 255) << 16) | ((qq[7] & 255) << 24);
      int2 pk; pk.x = (int)lo; pk.y = (int)hi;
      *(int2*)(VT8 + (long)(n0 + nn) * SEQ + m0 + c * 8) = pk;
    }
  }
}

__global__ __launch_bounds__(256) void score_kernel(
    const unsigned char* __restrict__ Q8, const unsigned char* __restrict__ K8,
    const float* __restrict__ sumsq,
    unsigned char* __restrict__ P8, float* __restrict__ denomq) {
  __shared__ unsigned short smem[16384];  // i8 As/Bs (16K+16K); epilogue reuses As as P tile
  unsigned char* As = (unsigned char*)smem;
  unsigned char* Bs = (unsigned char*)smem + 16384;
  const int m0 = blockIdx.y * 128;  // Q rows of this P8 tile
  const int n0 = blockIdx.x * 128;  // K cols of this P8 tile
  int16x acc[2][2];
#pragma unroll
  for (int i = 0; i < 2; ++i)
#pragma unroll
    for (int j = 0; j < 2; ++j)
#pragma unroll
      for (int e = 0; e < 16; ++e) acc[i][j][e] = 0;

  // Swapped operands: A = K8 (reg axis = K index), B = Q8 (lane axis = Q index).
  // acc[tm][tn][g*4+j] = dot(K8[n0 + wm + tm*32 + g*8 + lh*4 + j], Q8[m0 + wn + tn*32 + l31])
  gemm128_nt_i8(K8, Q8, MID, MID, n0, m0, MID, As, Bs, acc);

  const int tid = threadIdx.x;
  const int l = tid & 63, w = tid >> 6;
  const int wm = (w & 1) << 6, wn = (w >> 1) << 6;
  const int l31 = l & 31, lh = l >> 5;

  // Q-norm (lane axis): fold log2e here. exp(x)*ps = exp2(x*log2e + log2(ps)).
  const float LOG2E  = 1.4426950408889634f;
  const float LOG2PS = 5.5459896458832860f;  // log2(127/e)
  const float MAGIC  = 12582912.0f;          // 1.5 * 2^23
  float qi[2];
#pragma unroll
  for (int tn = 0; tn < 2; ++tn)
    qi[tn] = rsqrtf(sumsq[m0 + wn + tn * 32 + l31]) * LOG2E;

  __syncthreads();  // all waves done reading As/Bs

  unsigned char* Plds = As;  // 128x128 int8 P tile, 16B-granular XOR swizzle
#pragma unroll
  for (int tm = 0; tm < 2; ++tm) {
#pragma unroll
    for (int g = 0; g < 4; ++g) {
      const int nb = wm + tm * 32 + g * 8 + lh * 4;  // local K col base (4 consecutive)
      float4 ss4 = *(const float4*)(sumsq + SEQ + n0 + nb);
      float ik0 = rsqrtf(ss4.x), ik1 = rsqrtf(ss4.y);
      float ik2 = rsqrtf(ss4.z), ik3 = rsqrtf(ss4.w);
#pragma unroll
      for (int tn = 0; tn < 2; ++tn) {
        // q_j = RNE(exp(cos)*127/e) in [17,127]; low byte of (exp2(...) + 1.5*2^23)
        unsigned u0 = __float_as_uint(fexp2(fmaf((float)acc[tm][tn][g * 4 + 0] * ik0, qi[tn], LOG2PS)) + MAGIC);
        unsigned u1 = __float_as_uint(fexp2(fmaf((float)acc[tm][tn][g * 4 + 1] * ik1, qi[tn], LOG2PS)) + MAGIC);
        unsigned u2 = __float_as_uint(fexp2(fmaf((float)acc[tm][tn][g * 4 + 2] * ik2, qi[tn], LOG2PS)) + MAGIC);
        unsigned u3 = __float_as_uint(fexp2(fmaf((float)acc[tm][tn][g * 4 + 3] * ik3, qi[tn], LOG2PS)) + MAGIC);
        unsigned pk = (u0 & 255) | ((u1 & 255) << 8) | ((u2 & 255) << 16) | (u3 << 24);
        const int ml = wn + tn * 32 + l31;  // local Q row
        const int addr = ml * 128 + ((((nb >> 4) ^ (ml & 7)) << 4) | (nb & 15));
        *(unsigned*)(Plds + addr) = pk;
      }
    }
  }
  __syncthreads();

  // Readback: 32 rows/round x 8 threads/row; 16B per thread; denom = byte sum.
  const unsigned M8 = 0x00FF00FFu;
#pragma unroll
  for (int round = 0; round < 4; ++round) {
    const int row = round * 32 + (tid >> 3);
    const int c = tid & 7;
    const int addr = row * 128 + ((c ^ (row & 7)) << 4);
    uint4 v = *(const uint4*)(Plds + addr);
    unsigned e = (v.x & M8) + (v.y & M8) + (v.z & M8) + (v.w & M8);
    unsigned o = ((v.x >> 8) & M8) + ((v.y >> 8) & M8) + ((v.z >> 8) & M8) + ((v.w >> 8) & M8);
    unsigned t = e + o;
    unsigned s = (t & 0xFFFFu) + (t >> 16);
    *(uint4*)(P8 + (long)(m0 + row) * SEQ + n0 + c * 16) = v;
    s += __shfl_xor(s, 1); s += __shfl_xor(s, 2); s += __shfl_xor(s, 4);
    if (c == 0) atomicAdd(denomq + m0 + row, (float)s);
  }
}

__global__ __launch_bounds__(256) void out_kernel(
    const unsigned char* __restrict__ P8, const unsigned char* __restrict__ VT8,
    const float* __restrict__ denomq, float* __restrict__ out) {
  __shared__ unsigned char smem8[32768];  // i8 As/Bs 16K+16K
  unsigned char* As = smem8;
  unsigned char* Bs = smem8 + 16384;
  // grid: x = n (fast, 8), y = m (64) -> XCD = n%8: VT8 slice (1 MB) L2-pinned per XCD
  const int n0 = blockIdx.x * 128;
  const int m0 = blockIdx.y * 128;
  int16x acc[2][2];
#pragma unroll
  for (int i = 0; i < 2; ++i)
#pragma unroll
    for (int j = 0; j < 2; ++j)
#pragma unroll
      for (int e = 0; e < 16; ++e) acc[i][j][e] = 0;

  gemm128_nt_i8(P8, VT8, SEQ, SEQ, m0, n0, SEQ, As, Bs, acc);

  const int l = threadIdx.x & 63, w = threadIdx.x >> 6;
  const int wm = (w & 1) << 6, wn = (w >> 1) << 6;
  const int l31 = l & 31, lh = l >> 5;
  const float sv = 127.0f / 6.0f;
#pragma unroll
  for (int tm = 0; tm < 2; ++tm)
#pragma unroll
    for (int r = 0; r < 16; ++r) {
      const int row = m0 + wm + tm * 32 + (r & 3) + 8 * (r >> 2) + 4 * lh;
      const float inv = 1.0f / (sv * denomq[row]);   // out = sum(qP*qV) / (s_V * sum(qP))
#pragma unroll
      for (int tn = 0; tn < 2; ++tn) {
        const int col = n0 + wn + tn * 32 + l31;
        out[(long)row * MID + col] = (float)acc[tm][tn][r] * inv;
      }
    }
}

extern "C" void kernel_launch(void* const* d_in, const int* in_sizes, int n_in,
                              void* d_out, int out_size, void* d_ws, size_t ws_size,
                              hipStream_t stream) {
  const float* X  = (const float*)d_in[0];
  const float* Wq = (const float*)d_in[1];
  const float* bq = (const float*)d_in[2];
  const float* Wk = (const float*)d_in[3];
  const float* bk = (const float*)d_in[4];
  const float* Wv = (const float*)d_in[5];
  const float* bv = (const float*)d_in[6];

  // workspace layout (bytes). Xb/Wb alias the P8 region: dead before score writes P8.
  //  [0,8M)    Q8 int8 [8192][1024]
  //  [8M,16M)  K8 int8
  //  [16M,24M) VT8 int8 [1024][8192]
  //  [24M,..)  sumsq_q[8192], sumsq_k[8192], denomq[8192]  fp32 (zeroed by cvt_all)
  //  [25M,89M) P8 int8 [8192][8192];  Xb at 25M (16M), Wb at 41M (6M) alias inside
  char* wsb = (char*)d_ws;
  const size_t MB = 1ull << 20;
  unsigned char* Q8  = (unsigned char*)(wsb);
  unsigned char* K8  = (unsigned char*)(wsb + 8 * MB);
  unsigned char* VT8 = (unsigned char*)(wsb + 16 * MB);
  float* sums        = (float*)(wsb + 24 * MB);
  float* denomq      = sums + 2 * SEQ;
  unsigned char* P8  = (unsigned char*)(wsb + 25 * MB);
  unsigned short* Xb = (unsigned short*)(wsb + 25 * MB);
  unsigned short* Wb = (unsigned short*)(wsb + 41 * MB);

  const int cvt_elems = SEQ * EMB + 3 * MID * EMB;
  cvt_all<<<cvt_elems / 1024, 256, 0, stream>>>(X, Wq, Wk, Wv, Xb, Wb, sums);

  qkv_kernel<<<dim3(MID / 128, SEQ / 128, 3), 256, 0, stream>>>(Xb, Wb, bq, bk, bv, Q8, K8, VT8, sums);
  score_kernel<<<dim3(SEQ / 128, SEQ / 128), 256, 0, stream>>>(Q8, K8, sums, P8, denomq);
  out_kernel<<<dim3(MID / 128, SEQ / 128), 256, 0, stream>>>(P8, VT8, denomq, (float*)d_out);
}

// Round 6
// 334.453 us; speedup vs baseline: 1.2243x; 1.0288x over previous
//
#include <hip/hip_runtime.h>

// SelfAttention: X[8192,1024] -> Q,K,V = X@W^T+b ; P=exp(cosine(Q,K)) ; out = P@V / rowsum(P)
// R13: score epilogue rewrite (operand swap + magic-quantize + byte-sum denom): 409 -> 344 us,
//      score 186 -> 101 us, MfmaUtil 15.6 -> 29.3%, absmax 9.16e-4.
// R14/R15/R16: occupancy experiment (R14/R15 benches lost to infra; identical resubmit #3).
//      score shows VGPR 84 + AGPR 64 = 148 unified regs -> 3 waves/SIMD (512/148).
//      The serial 2-barrier core hides its staging drain only via cross-block wave
//      overlap (m114), so resident waves are the direct lever.
//      __launch_bounds__(256, 4) on score_kernel + out_kernel caps regs at 128/wave ->
//      4 waves/SIMD (+33% residency). qkv_kernel left UNTREATED as a control (same 148-reg
//      profile) for clean attribution in the next counter read.
//      Predict: score VGPR->~64, Occupancy 28->~40%, MfmaUtil 29->~37%, score ~85 us,
//      total ~305-315 us. Spill signature = VGPR capped but dur up -> revert.

#define SEQ 8192
#define MID 1024
#define EMB 1024

typedef __attribute__((ext_vector_type(8))) short short8x;
typedef __attribute__((ext_vector_type(16))) float float16x;
typedef __attribute__((ext_vector_type(4))) int int4x;
typedef __attribute__((ext_vector_type(16))) int int16x;

__device__ __forceinline__ unsigned short f2bf(float x) {
  union { float f; unsigned u; } v; v.f = x;
  unsigned r = v.u + 0x7FFFu + ((v.u >> 16) & 1u);  // round-to-nearest-even
  return (unsigned short)(r >> 16);
}
__device__ __forceinline__ float bf2f(unsigned short h) {
  union { unsigned u; float f; } v; v.u = ((unsigned)h) << 16;
  return v.f;
}
__device__ __forceinline__ float fexp2(float x) {
#if __has_builtin(__builtin_amdgcn_exp2f)
  return __builtin_amdgcn_exp2f(x);
#else
  return __expf(x * 0.6931471805599453f);
#endif
}

__device__ __forceinline__ void g2l16(const void* g, void* lds) {
  __builtin_amdgcn_global_load_lds(
      (const __attribute__((address_space(1))) unsigned int*)g,
      (__attribute__((address_space(3))) unsigned int*)lds, 16, 0, 0);
}

// ---------------- 128x128 bf16 NT GEMM core (qkv) ----------------
__device__ __forceinline__ void gemm128_nt(
    const unsigned short* __restrict__ A, const unsigned short* __restrict__ B,
    long lda, long ldb, int m0, int n0, int K,
    unsigned short* As, unsigned short* Bs, float16x acc[2][2]) {
  const int tid = threadIdx.x;
  const int w = tid >> 6;
  const int l = tid & 63;
  const int wm = (w & 1) << 6;
  const int wn = (w >> 1) << 6;
  const int srow = l >> 3;
  const int skg = (l & 7) ^ srow;
  const int l31 = l & 31;
  const int lh = l >> 5;
  const int swz = l31 & 7;

  for (int k0 = 0; k0 < K; k0 += 64) {
    __syncthreads();
#pragma unroll
    for (int r = 0; r < 4; ++r) {
      const int rr = (w * 4 + r) * 8 + srow;
      g2l16(A + (long)(m0 + rr) * lda + k0 + skg * 8, As + (w * 4 + r) * 512);
      g2l16(B + (long)(n0 + rr) * ldb + k0 + skg * 8, Bs + (w * 4 + r) * 512);
    }
    __syncthreads();
#pragma unroll
    for (int ks = 0; ks < 4; ++ks) {
      const int kg = ks * 2 + lh;
      short8x av[2], bv[2];
#pragma unroll
      for (int t = 0; t < 2; ++t) {
        av[t] = *(const short8x*)(As + (wm + t * 32 + l31) * 64 + ((kg ^ swz) << 3));
        bv[t] = *(const short8x*)(Bs + (wn + t * 32 + l31) * 64 + ((kg ^ swz) << 3));
      }
#pragma unroll
      for (int tm = 0; tm < 2; ++tm)
#pragma unroll
        for (int tn = 0; tn < 2; ++tn)
          acc[tm][tn] = __builtin_amdgcn_mfma_f32_32x32x16_bf16(av[tm], bv[tn], acc[tm][tn], 0, 0, 0);
    }
  }
}

// ---------------- 128x128 i8 NT GEMM core (score, out) — R9-proven ----------------
__device__ __forceinline__ void gemm128_nt_i8(
    const unsigned char* __restrict__ A, const unsigned char* __restrict__ B,
    long lda, long ldb, int m0, int n0, int Kbytes,
    unsigned char* As, unsigned char* Bs, int16x acc[2][2]) {
  const int tid = threadIdx.x;
  const int w = tid >> 6;
  const int l = tid & 63;
  const int wm = (w & 1) << 6;
  const int wn = (w >> 1) << 6;
  const int srow = l >> 3;
  const int skg = (l & 7) ^ srow;
  const int l31 = l & 31;
  const int lh = l >> 5;
  const int swz = l31 & 7;

  for (int k0 = 0; k0 < Kbytes; k0 += 128) {
    __syncthreads();
#pragma unroll
    for (int r = 0; r < 4; ++r) {
      const int rr = (w * 4 + r) * 8 + srow;
      g2l16(A + (long)(m0 + rr) * lda + k0 + skg * 16, As + (w * 4 + r) * 1024);
      g2l16(B + (long)(n0 + rr) * ldb + k0 + skg * 16, Bs + (w * 4 + r) * 1024);
    }
    __syncthreads();
#pragma unroll
    for (int ks = 0; ks < 4; ++ks) {
      const int kg = ks * 2 + lh;
      int4x av[2], bv[2];
#pragma unroll
      for (int t = 0; t < 2; ++t) {
        av[t] = *(const int4x*)(As + (wm + t * 32 + l31) * 128 + ((kg ^ swz) << 4));
        bv[t] = *(const int4x*)(Bs + (wn + t * 32 + l31) * 128 + ((kg ^ swz) << 4));
      }
#pragma unroll
      for (int tm = 0; tm < 2; ++tm)
#pragma unroll
        for (int tn = 0; tn < 2; ++tn)
          acc[tm][tn] = __builtin_amdgcn_mfma_i32_32x32x32_i8(av[tm], bv[tn], acc[tm][tn], 0, 0, 0);
    }
  }
}

// One launch: convert X + Wq/Wk/Wv to bf16, and zero sums (24576 floats).
__global__ void cvt_all(const float* __restrict__ X,
                        const float* __restrict__ wq, const float* __restrict__ wk,
                        const float* __restrict__ wv,
                        unsigned short* __restrict__ Xb, unsigned short* __restrict__ Wb,
                        float* __restrict__ sums) {
  const long i = ((long)blockIdx.x * 256 + threadIdx.x) * 4;
  if (i < 24576) *(float4*)(sums + i) = (float4){0.f, 0.f, 0.f, 0.f};
  const float* src;
  unsigned short* dst;
  long off;
  if (i < (long)SEQ * EMB) {
    src = X; dst = Xb; off = i;
  } else {
    long j = i - (long)SEQ * EMB;
    int t = (int)(j >> 20);
    off = j & (MID * EMB - 1);
    src = (t == 0) ? wq : (t == 1) ? wk : wv;
    dst = Wb + (long)t * MID * EMB;
  }
  float4 v = *(const float4*)(src + off);
  ushort4 o;
  o.x = f2bf(v.x); o.y = f2bf(v.y); o.z = f2bf(v.z); o.w = f2bf(v.w);
  *(ushort4*)(dst + off) = o;
}

__global__ __launch_bounds__(256) void qkv_kernel(
    const unsigned short* __restrict__ Xb, const unsigned short* __restrict__ Wb,
    const float* __restrict__ bq, const float* __restrict__ bk, const float* __restrict__ bv,
    unsigned char* __restrict__ Q8, unsigned char* __restrict__ K8,
    unsigned char* __restrict__ VT8, float* __restrict__ sumsq) {
  __shared__ unsigned short smem[16384];
  unsigned short* As = smem;
  unsigned short* Bs = smem + 8192;
  const int z = blockIdx.z;
  const int m0 = blockIdx.y * 128;
  const int n0 = blockIdx.x * 128;
  float16x acc[2][2];
#pragma unroll
  for (int i = 0; i < 2; ++i)
#pragma unroll
    for (int j = 0; j < 2; ++j)
#pragma unroll
      for (int e = 0; e < 16; ++e) acc[i][j][e] = 0.f;

  gemm128_nt(Xb, Wb + (long)z * MID * EMB, EMB, EMB, m0, n0, EMB, As, Bs, acc);

  const int tid = threadIdx.x;
  const int l = tid & 63, w = tid >> 6;
  const int wm = (w & 1) << 6, wn = (w >> 1) << 6;
  const int l31 = l & 31, lh = l >> 5;
  const float* bias = (z == 0) ? bq : (z == 1) ? bk : bv;
  float bvv[2];
#pragma unroll
  for (int tn = 0; tn < 2; ++tn) bvv[tn] = bias[n0 + wn + tn * 32 + l31];
#pragma unroll
  for (int tm = 0; tm < 2; ++tm)
#pragma unroll
    for (int tn = 0; tn < 2; ++tn)
#pragma unroll
      for (int r = 0; r < 16; ++r) acc[tm][tn][r] += bvv[tn];

  __syncthreads();  // all waves done reading As/Bs

  if (z < 2) {
    // bf16 transpose tile, then readback -> int8 quantize + int-sumsq (R9-proven)
#pragma unroll
    for (int tm = 0; tm < 2; ++tm)
#pragma unroll
      for (int tn = 0; tn < 2; ++tn) {
        const int rcol = wn + tn * 32 + l31;
#pragma unroll
        for (int r = 0; r < 16; ++r) {
          float v = acc[tm][tn][r];
          float po = __shfl_xor(v, 1);
          if (!(l & 1)) {
            const int rrow = wm + tm * 32 + (r & 3) + 8 * (r >> 2) + 4 * lh;
            const int chunk = (rcol >> 3) ^ (rrow & 7);
            unsigned pk = (unsigned)f2bf(v) | ((unsigned)f2bf(po) << 16);
            *(unsigned*)(smem + rrow * 128 + (chunk << 3) + (rcol & 7)) = pk;
          }
        }
      }
    __syncthreads();
    unsigned char* O8 = z ? K8 : Q8;
    float* ss = sumsq + (long)z * SEQ;
    const float qs = 127.0f / 8.0f;
#pragma unroll
    for (int round = 0; round < 8; ++round) {
      const int row = round * 16 + (tid >> 4);
      const int c = tid & 15;
      short8x vv = *(const short8x*)(smem + row * 128 + ((c ^ (row & 7)) << 3));
      int qq[8];
      float s = 0.f;
#pragma unroll
      for (int j = 0; j < 8; ++j) {
        float t = rintf(bf2f((unsigned short)vv[j]) * qs);
        t = fminf(127.f, fmaxf(-127.f, t));
        qq[j] = (int)t;
        s += t * t;
      }
      unsigned lo = (qq[0] & 255) | ((qq[1] & 255) << 8) | ((qq[2] & 255) << 16) | ((qq[3] & 255) << 24);
      unsigned hi = (qq[4] & 255) | ((qq[5] & 255) << 8) | ((qq[6] & 255) << 16) | ((qq[7] & 255) << 24);
      int2 pk; pk.x = (int)lo; pk.y = (int)hi;
      *(int2*)(O8 + (long)(m0 + row) * MID + n0 + c * 8) = pk;
      s += __shfl_xor(s, 1); s += __shfl_xor(s, 2);
      s += __shfl_xor(s, 4); s += __shfl_xor(s, 8);
      if (c == 0) atomicAdd(ss + m0 + row, s);
    }
  } else {
    // V transposed, int8: bf16 LDS tile [nn][mm] (proven), readback -> quantize -> VT8
#pragma unroll
    for (int tm = 0; tm < 2; ++tm)
#pragma unroll
      for (int tn = 0; tn < 2; ++tn) {
        const int nn = wn + tn * 32 + l31;
#pragma unroll
        for (int g = 0; g < 4; ++g) {
          const int mm = wm + tm * 32 + 8 * g + 4 * lh;
          const int chunk = (mm >> 3) ^ (nn & 7);
          ushort4 pk;
          pk.x = f2bf(acc[tm][tn][g * 4 + 0]);
          pk.y = f2bf(acc[tm][tn][g * 4 + 1]);
          pk.z = f2bf(acc[tm][tn][g * 4 + 2]);
          pk.w = f2bf(acc[tm][tn][g * 4 + 3]);
          *(ushort4*)(smem + nn * 128 + (chunk << 3) + (mm & 7)) = pk;
        }
      }
    __syncthreads();
    const float vs = 127.0f / 6.0f;  // |V| <= ~5.5 over 8M N(0,1)-ish samples
#pragma unroll
    for (int round = 0; round < 8; ++round) {
      const int nn = round * 16 + (tid >> 4);
      const int c = tid & 15;
      short8x vv = *(const short8x*)(smem + nn * 128 + ((c ^ (nn & 7)) << 3));
      int qq[8];
#pragma unroll
      for (int j = 0; j < 8; ++j) {
        float t = rintf(bf2f((unsigned short)vv[j]) * vs);
        t = fminf(127.f, fmaxf(-127.f, t));
        qq[j] = (int)t;
      }
      unsigned lo = (qq[0] & 255) | ((qq[1] & 255) << 8) | ((qq[2] & 255) << 16) | ((qq[3] & 255) << 24);
      unsigned hi = (qq[4] & 255) | ((qq[5] & 255) << 8) | ((qq[6] & 255) << 16) | ((qq[7] & 255) << 24);
      int2 pk; pk.x = (int)lo; pk.y = (int)hi;
      *(int2*)(VT8 + (long)(n0 + nn) * SEQ + m0 + c * 8) = pk;
    }
  }
}

__global__ __launch_bounds__(256, 4) void score_kernel(
    const unsigned char* __restrict__ Q8, const unsigned char* __restrict__ K8,
    const float* __restrict__ sumsq,
    unsigned char* __restrict__ P8, float* __restrict__ denomq) {
  __shared__ unsigned short smem[16384];  // i8 As/Bs (16K+16K); epilogue reuses As as P tile
  unsigned char* As = (unsigned char*)smem;
  unsigned char* Bs = (unsigned char*)smem + 16384;
  const int m0 = blockIdx.y * 128;  // Q rows of this P8 tile
  const int n0 = blockIdx.x * 128;  // K cols of this P8 tile
  int16x acc[2][2];
#pragma unroll
  for (int i = 0; i < 2; ++i)
#pragma unroll
    for (int j = 0; j < 2; ++j)
#pragma unroll
      for (int e = 0; e < 16; ++e) acc[i][j][e] = 0;

  // Swapped operands: A = K8 (reg axis = K index), B = Q8 (lane axis = Q index).
  // acc[tm][tn][g*4+j] = dot(K8[n0 + wm + tm*32 + g*8 + lh*4 + j], Q8[m0 + wn + tn*32 + l31])
  gemm128_nt_i8(K8, Q8, MID, MID, n0, m0, MID, As, Bs, acc);

  const int tid = threadIdx.x;
  const int l = tid & 63, w = tid >> 6;
  const int wm = (w & 1) << 6, wn = (w >> 1) << 6;
  const int l31 = l & 31, lh = l >> 5;

  // Q-norm (lane axis): fold log2e here. exp(x)*ps = exp2(x*log2e + log2(ps)).
  const float LOG2E  = 1.4426950408889634f;
  const float LOG2PS = 5.5459896458832860f;  // log2(127/e)
  const float MAGIC  = 12582912.0f;          // 1.5 * 2^23
  float qi[2];
#pragma unroll
  for (int tn = 0; tn < 2; ++tn)
    qi[tn] = rsqrtf(sumsq[m0 + wn + tn * 32 + l31]) * LOG2E;

  __syncthreads();  // all waves done reading As/Bs

  unsigned char* Plds = As;  // 128x128 int8 P tile, 16B-granular XOR swizzle
#pragma unroll
  for (int tm = 0; tm < 2; ++tm) {
#pragma unroll
    for (int g = 0; g < 4; ++g) {
      const int nb = wm + tm * 32 + g * 8 + lh * 4;  // local K col base (4 consecutive)
      float4 ss4 = *(const float4*)(sumsq + SEQ + n0 + nb);
      float ik0 = rsqrtf(ss4.x), ik1 = rsqrtf(ss4.y);
      float ik2 = rsqrtf(ss4.z), ik3 = rsqrtf(ss4.w);
#pragma unroll
      for (int tn = 0; tn < 2; ++tn) {
        // q_j = RNE(exp(cos)*127/e) in [17,127]; low byte of (exp2(...) + 1.5*2^23)
        unsigned u0 = __float_as_uint(fexp2(fmaf((float)acc[tm][tn][g * 4 + 0] * ik0, qi[tn], LOG2PS)) + MAGIC);
        unsigned u1 = __float_as_uint(fexp2(fmaf((float)acc[tm][tn][g * 4 + 1] * ik1, qi[tn], LOG2PS)) + MAGIC);
        unsigned u2 = __float_as_uint(fexp2(fmaf((float)acc[tm][tn][g * 4 + 2] * ik2, qi[tn], LOG2PS)) + MAGIC);
        unsigned u3 = __float_as_uint(fexp2(fmaf((float)acc[tm][tn][g * 4 + 3] * ik3, qi[tn], LOG2PS)) + MAGIC);
        unsigned pk = (u0 & 255) | ((u1 & 255) << 8) | ((u2 & 255) << 16) | (u3 << 24);
        const int ml = wn + tn * 32 + l31;  // local Q row
        const int addr = ml * 128 + ((((nb >> 4) ^ (ml & 7)) << 4) | (nb & 15));
        *(unsigned*)(Plds + addr) = pk;
      }
    }
  }
  __syncthreads();

  // Readback: 32 rows/round x 8 threads/row; 16B per thread; denom = byte sum.
  const unsigned M8 = 0x00FF00FFu;
#pragma unroll
  for (int round = 0; round < 4; ++round) {
    const int row = round * 32 + (tid >> 3);
    const int c = tid & 7;
    const int addr = row * 128 + ((c ^ (row & 7)) << 4);
    uint4 v = *(const uint4*)(Plds + addr);
    unsigned e = (v.x & M8) + (v.y & M8) + (v.z & M8) + (v.w & M8);
    unsigned o = ((v.x >> 8) & M8) + ((v.y >> 8) & M8) + ((v.z >> 8) & M8) + ((v.w >> 8) & M8);
    unsigned t = e + o;
    unsigned s = (t & 0xFFFFu) + (t >> 16);
    *(uint4*)(P8 + (long)(m0 + row) * SEQ + n0 + c * 16) = v;
    s += __shfl_xor(s, 1); s += __shfl_xor(s, 2); s += __shfl_xor(s, 4);
    if (c == 0) atomicAdd(denomq + m0 + row, (float)s);
  }
}

__global__ __launch_bounds__(256, 4) void out_kernel(
    const unsigned char* __restrict__ P8, const unsigned char* __restrict__ VT8,
    const float* __restrict__ denomq, float* __restrict__ out) {
  __shared__ unsigned char smem8[32768];  // i8 As/Bs 16K+16K
  unsigned char* As = smem8;
  unsigned char* Bs = smem8 + 16384;
  // grid: x = n (fast, 8), y = m (64) -> XCD = n%8: VT8 slice (1 MB) L2-pinned per XCD
  const int n0 = blockIdx.x * 128;
  const int m0 = blockIdx.y * 128;
  int16x acc[2][2];
#pragma unroll
  for (int i = 0; i < 2; ++i)
#pragma unroll
    for (int j = 0; j < 2; ++j)
#pragma unroll
      for (int e = 0; e < 16; ++e) acc[i][j][e] = 0;

  gemm128_nt_i8(P8, VT8, SEQ, SEQ, m0, n0, SEQ, As, Bs, acc);

  const int l = threadIdx.x & 63, w = threadIdx.x >> 6;
  const int wm = (w & 1) << 6, wn = (w >> 1) << 6;
  const int l31 = l & 31, lh = l >> 5;
  const float sv = 127.0f / 6.0f;
#pragma unroll
  for (int tm = 0; tm < 2; ++tm)
#pragma unroll
    for (int r = 0; r < 16; ++r) {
      const int row = m0 + wm + tm * 32 + (r & 3) + 8 * (r >> 2) + 4 * lh;
      const float inv = 1.0f / (sv * denomq[row]);   // out = sum(qP*qV) / (s_V * sum(qP))
#pragma unroll
      for (int tn = 0; tn < 2; ++tn) {
        const int col = n0 + wn + tn * 32 + l31;
        out[(long)row * MID + col] = (float)acc[tm][tn][r] * inv;
      }
    }
}

extern "C" void kernel_launch(void* const* d_in, const int* in_sizes, int n_in,
                              void* d_out, int out_size, void* d_ws, size_t ws_size,
                              hipStream_t stream) {
  const float* X  = (const float*)d_in[0];
  const float* Wq = (const float*)d_in[1];
  const float* bq = (const float*)d_in[2];
  const float* Wk = (const float*)d_in[3];
  const float* bk = (const float*)d_in[4];
  const float* Wv = (const float*)d_in[5];
  const float* bv = (const float*)d_in[6];

  // workspace layout (bytes). Xb/Wb alias the P8 region: dead before score writes P8.
  //  [0,8M)    Q8 int8 [8192][1024]
  //  [8M,16M)  K8 int8
  //  [16M,24M) VT8 int8 [1024][8192]
  //  [24M,..)  sumsq_q[8192], sumsq_k[8192], denomq[8192]  fp32 (zeroed by cvt_all)
  //  [25M,89M) P8 int8 [8192][8192];  Xb at 25M (16M), Wb at 41M (6M) alias inside
  char* wsb = (char*)d_ws;
  const size_t MB = 1ull << 20;
  unsigned char* Q8  = (unsigned char*)(wsb);
  unsigned char* K8  = (unsigned char*)(wsb + 8 * MB);
  unsigned char* VT8 = (unsigned char*)(wsb + 16 * MB);
  float* sums        = (float*)(wsb + 24 * MB);
  float* denomq      = sums + 2 * SEQ;
  unsigned char* P8  = (unsigned char*)(wsb + 25 * MB);
  unsigned short* Xb = (unsigned short*)(wsb + 25 * MB);
  unsigned short* Wb = (unsigned short*)(wsb + 41 * MB);

  const int cvt_elems = SEQ * EMB + 3 * MID * EMB;
  cvt_all<<<cvt_elems / 1024, 256, 0, stream>>>(X, Wq, Wk, Wv, Xb, Wb, sums);

  qkv_kernel<<<dim3(MID / 128, SEQ / 128, 3), 256, 0, stream>>>(Xb, Wb, bq, bk, bv, Q8, K8, VT8, sums);
  score_kernel<<<dim3(SEQ / 128, SEQ / 128), 256, 0, stream>>>(Q8, K8, sums, P8, denomq);
  out_kernel<<<dim3(MID / 128, SEQ / 128), 256, 0, stream>>>(P8, VT8, denomq, (float*)d_out);
}